// Round 5
// baseline (555.869 us; speedup 1.0000x reference)
//
#include <hip/hip_runtime.h>
#include <hip/hip_bf16.h>

typedef __bf16 bf16;
typedef bf16 bf16x8 __attribute__((ext_vector_type(8)));
typedef bf16 bf16x4v __attribute__((ext_vector_type(4)));
typedef bf16 bf16x2 __attribute__((ext_vector_type(2)));
typedef float f32x4 __attribute__((ext_vector_type(4)));

#define BB 8
#define CC 192
#define NH 6
#define HWN 16384
#define KSPLIT 16
#define KLEN (HWN / KSPLIT) /* 1024 */
#define KC 64
#define GN (3 * BB * CC * CC)  /* 884736 floats per gram set */
#define ZN (BB * CC * CC)      /* 294912 */
#define YTN ((size_t)BB * HWN * CC) /* 25165824 bf16 */

// ---------------------------------------------------------------------------
// Merged gram kernel: for (ks, b, nh) computes 3 types x [192 rows][96 cols]
// partial Gram over K-slab ks. type 0: X*Y^T, 1: X*X^T, 2: Y*Y^T.
// 512 thr = 8 waves; wave tile 48x48 per type; acc 108 VGPRs.
// ---------------------------------------------------------------------------
__global__ __launch_bounds__(512, 2) void gram_kernel(
    const float* __restrict__ x, const float* __restrict__ y,
    float* __restrict__ dst, int use_atomic)
{
  const int ks = blockIdx.x, b = blockIdx.y, nh = blockIdx.z;
  const int tid = threadIdx.x;
  const int lane = tid & 63, w = tid >> 6;
  const int rowbase = (w >> 1) * 48;
  const int colbase = nh * 96 + (w & 1) * 48;
  const int lo = lane & 15, hi = lane >> 4;

  __shared__ bf16 tX[CC * KC];  // [192][64], row 128 B, XOR-swizzled
  __shared__ bf16 tY[CC * KC];

  f32x4 acc[3][3][3];  // [type][mt][nt]
  #pragma unroll
  for (int t3 = 0; t3 < 3; ++t3)
    #pragma unroll
    for (int m = 0; m < 3; ++m)
      #pragma unroll
      for (int n = 0; n < 3; ++n) acc[t3][m][n] = (f32x4){0.f, 0.f, 0.f, 0.f};

  const int k0 = ks * KLEN;

  for (int ch = 0; ch < KLEN / KC; ++ch) {
    const int nbase = k0 + ch * KC;
    #pragma unroll
    for (int i = 0; i < 6; ++i) {
      int s = tid + 512 * i;
      int r = s >> 4, c4 = s & 15;
      size_t goff = ((size_t)(b * CC + r)) * HWN + nbase + c4 * 4;
      const float4 vx = *(const float4*)(x + goff);
      const float4 vy = *(const float4*)(y + goff);
      int byte = (r * 128 + c4 * 8) ^ ((r & 7) << 4);
      *(bf16x4v*)((char*)tX + byte) = (bf16x4v){(bf16)vx.x, (bf16)vx.y, (bf16)vx.z, (bf16)vx.w};
      *(bf16x4v*)((char*)tY + byte) = (bf16x4v){(bf16)vy.x, (bf16)vy.y, (bf16)vy.z, (bf16)vy.w};
    }
    __syncthreads();

    #pragma unroll
    for (int kk = 0; kk < KC; kk += 32) {
      const int kb = (kk + hi * 8) * 2;
      bf16x8 aX[3], aY[3], bX[3], bY[3];
      #pragma unroll
      for (int mt = 0; mt < 3; ++mt) {
        int rA = rowbase + mt * 16 + lo;
        int byte = (rA * 128 + kb) ^ ((rA & 7) << 4);
        aX[mt] = *(const bf16x8*)((const char*)tX + byte);
        aY[mt] = *(const bf16x8*)((const char*)tY + byte);
      }
      #pragma unroll
      for (int nt = 0; nt < 3; ++nt) {
        int rB = colbase + nt * 16 + lo;
        int byte = (rB * 128 + kb) ^ ((rB & 7) << 4);
        bX[nt] = *(const bf16x8*)((const char*)tX + byte);
        bY[nt] = *(const bf16x8*)((const char*)tY + byte);
      }
      #pragma unroll
      for (int mt = 0; mt < 3; ++mt)
        #pragma unroll
        for (int nt = 0; nt < 3; ++nt) {
          acc[0][mt][nt] = __builtin_amdgcn_mfma_f32_16x16x32_bf16(aX[mt], bY[nt], acc[0][mt][nt], 0, 0, 0);
          acc[1][mt][nt] = __builtin_amdgcn_mfma_f32_16x16x32_bf16(aX[mt], bX[nt], acc[1][mt][nt], 0, 0, 0);
          acc[2][mt][nt] = __builtin_amdgcn_mfma_f32_16x16x32_bf16(aY[mt], bY[nt], acc[2][mt][nt], 0, 0, 0);
        }
    }
    __syncthreads();
  }

  // C/D layout: col = lane&15, row = (lane>>4)*4 + reg
  #pragma unroll
  for (int t3 = 0; t3 < 3; ++t3) {
    float* gb = dst + (use_atomic ? 0 : (size_t)ks * GN) + ((size_t)(t3 * BB + b)) * CC * CC;
    #pragma unroll
    for (int mt = 0; mt < 3; ++mt)
      #pragma unroll
      for (int nt = 0; nt < 3; ++nt)
        #pragma unroll
        for (int r = 0; r < 4; ++r) {
          int rm = rowbase + mt * 16 + hi * 4 + r;
          int cn = colbase + nt * 16 + lo;
          if (use_atomic) atomicAdd(gb + rm * CC + cn, acc[t3][mt][nt][r]);
          else            gb[rm * CC + cn] = acc[t3][mt][nt][r];
        }
  }
}

// Sum KSPLIT partial slabs -> gram.
__global__ void reduce_kernel(const float* __restrict__ gpart, float* __restrict__ gram)
{
  const size_t i = (size_t)blockIdx.x * 256 + threadIdx.x;
  float a = 0.f;
  #pragma unroll
  for (int s = 0; s < KSPLIT; ++s) a += gpart[(size_t)s * GN + i];
  gram[i] = a;
}

// ---------------------------------------------------------------------------
// s1: TUV[type][b] = gram[type][b] * Wsel^T   (192x192x192 fp32)
// ---------------------------------------------------------------------------
__global__ void s1_kernel(const float* __restrict__ gram, const float* __restrict__ Wq,
                          const float* __restrict__ Wk, float* __restrict__ tuv)
{
  const int rc = blockIdx.x, b = blockIdx.y, type = blockIdx.z;
  const float* W = (type == 1) ? Wq : Wk;
  const float* G = gram + ((size_t)(type * BB + b)) * CC * CC;
  float* T = tuv + ((size_t)(type * BB + b)) * CC * CC;
  const int d = threadIdx.x;
  const int r0 = rc * 24;
  float acc[24];
  #pragma unroll
  for (int i = 0; i < 24; ++i) acc[i] = 0.f;
  for (int dc = 0; dc < 4; ++dc) {
    float4 w4[12];
    const float4* wp = (const float4*)(W + d * CC + dc * 48);
    #pragma unroll
    for (int j = 0; j < 12; ++j) w4[j] = wp[j];
    for (int ci = 0; ci < 24; ++ci) {
      const float4* g4 = (const float4*)(G + (r0 + ci) * CC + dc * 48);
      float a = acc[ci];
      #pragma unroll
      for (int j = 0; j < 12; ++j) {
        float4 g = g4[j];
        a += g.x * w4[j].x + g.y * w4[j].y + g.z * w4[j].z + g.w * w4[j].w;
      }
      acc[ci] = a;
    }
  }
  #pragma unroll
  for (int ci = 0; ci < 24; ++ci) T[(r0 + ci) * CC + d] = acc[ci];
}

// ---------------------------------------------------------------------------
// s2: per (b,head): S, norms, softmax, Z_head = A * Wv_head_rows.
// ---------------------------------------------------------------------------
__global__ void s2_kernel(const float* __restrict__ tuv, const float* __restrict__ Wq,
                          const float* __restrict__ Wk, const float* __restrict__ Wv,
                          const float* __restrict__ temperature, float* __restrict__ z)
{
  const int h = blockIdx.x, b = blockIdx.y;
  const int tid = threadIdx.x;
  const float* T  = tuv + ((size_t)(0 * BB + b)) * CC * CC;
  const float* U  = tuv + ((size_t)(1 * BB + b)) * CC * CC;
  const float* V2 = tuv + ((size_t)(2 * BB + b)) * CC * CC;
  __shared__ float sA[32][33];
  __shared__ float snq[32];
  __shared__ float snk[32];

  const int dd = tid & 31, cg = tid >> 5;
  float s[4] = {0.f, 0.f, 0.f, 0.f};
  for (int cp = 0; cp < CC; ++cp) {
    float tv = T[cp * CC + h * 32 + dd];
    #pragma unroll
    for (int i = 0; i < 4; ++i)
      s[i] += Wq[(h * 32 + cg + 8 * i) * CC + cp] * tv;
  }
  if (tid < 32) {
    float a = 0.f;
    for (int cp = 0; cp < CC; ++cp)
      a += Wq[(h * 32 + tid) * CC + cp] * U[cp * CC + h * 32 + tid];
    snq[tid] = fmaxf(sqrtf(fmaxf(a, 0.f)), 1e-12f);
  } else if (tid < 64) {
    int t2 = tid - 32;
    float a = 0.f;
    for (int cp = 0; cp < CC; ++cp)
      a += Wk[(h * 32 + t2) * CC + cp] * V2[cp * CC + h * 32 + t2];
    snk[t2] = fmaxf(sqrtf(fmaxf(a, 0.f)), 1e-12f);
  }
  __syncthreads();

  const float temp = temperature[h];
  const float rk = 1.f / snk[dd];
  #pragma unroll
  for (int i = 0; i < 4; ++i) {
    int ccr = cg + 8 * i;
    float l = s[i] * (1.f / snq[ccr]) * rk * temp;
    float m = l;
    #pragma unroll
    for (int msk = 16; msk >= 1; msk >>= 1) m = fmaxf(m, __shfl_xor(m, msk));
    float p = expf(l - m);
    float su = p;
    #pragma unroll
    for (int msk = 16; msk >= 1; msk >>= 1) su += __shfl_xor(su, msk);
    sA[ccr][dd] = p / su;
  }
  __syncthreads();

  const int c2l = tid & 63, ccg = tid >> 6;
  float za[8][3];
  #pragma unroll
  for (int i = 0; i < 8; ++i)
    #pragma unroll
    for (int j = 0; j < 3; ++j) za[i][j] = 0.f;
  for (int d2 = 0; d2 < 32; ++d2) {
    float wv[3];
    #pragma unroll
    for (int j = 0; j < 3; ++j) wv[j] = Wv[(h * 32 + d2) * CC + c2l + 64 * j];
    #pragma unroll
    for (int i = 0; i < 8; ++i) {
      float a = sA[ccg * 8 + i][d2];
      #pragma unroll
      for (int j = 0; j < 3; ++j) za[i][j] += a * wv[j];
    }
  }
  #pragma unroll
  for (int i = 0; i < 8; ++i)
    #pragma unroll
    for (int j = 0; j < 3; ++j)
      z[((size_t)b * CC + h * 32 + ccg * 8 + i) * CC + c2l + 64 * j] = za[i][j];
}

// ---------------------------------------------------------------------------
// s3: P[b][o][d] = (Wo * Z_b)[o][d], emitted as bf16 for f_kernel's A operand.
// ---------------------------------------------------------------------------
__global__ void s3_kernel(const float* __restrict__ z, const float* __restrict__ Wo,
                          bf16* __restrict__ pb)
{
  const int oc = blockIdx.x, b = blockIdx.y;
  const int d = threadIdx.x;  // 0..191
  const int o0 = oc * 24;
  const float* Z = z + (size_t)b * CC * CC;
  float acc[24];
  #pragma unroll
  for (int i = 0; i < 24; ++i) acc[i] = 0.f;
  for (int c = 0; c < CC; ++c) {
    float zv = Z[c * CC + d];
    #pragma unroll
    for (int oi = 0; oi < 24; ++oi)
      acc[oi] += Wo[(o0 + oi) * CC + c] * zv;
  }
  bf16* P = pb + (size_t)b * CC * CC;
  #pragma unroll
  for (int oi = 0; oi < 24; ++oi)
    P[(o0 + oi) * CC + d] = (bf16)acc[oi];
}

// ---------------------------------------------------------------------------
// tr: yT[b][n][d] = bf16(Y[b][d][n]).  Block (nc,b): 64 n x 192 d tile.
// Stage [d][n] pitch 66 (b32 writes, ~2-way), column-gather (~4-way),
// fully coalesced bf16x8 global stores.
// ---------------------------------------------------------------------------
__global__ __launch_bounds__(256) void tr_kernel(const float* __restrict__ y,
                                                 bf16* __restrict__ yt)
{
  const int nc = blockIdx.x, b = blockIdx.y;
  const int tid = threadIdx.x;
  __shared__ bf16 t[CC * 66];
  #pragma unroll
  for (int i = 0; i < 12; ++i) {
    int s = tid + 256 * i;
    int r = s >> 4, c4 = (s & 15) * 4;
    const float4 v = *(const float4*)(y + ((size_t)(b * CC + r)) * HWN + nc * 64 + c4);
    bf16* p = t + r * 66 + c4;
    *(bf16x2*)(p)     = (bf16x2){(bf16)v.x, (bf16)v.y};
    *(bf16x2*)(p + 2) = (bf16x2){(bf16)v.z, (bf16)v.w};
  }
  __syncthreads();
  const int n = tid >> 2, seg = tid & 3;
  bf16* dstrow = yt + ((size_t)b * HWN + nc * 64 + n) * CC + seg * 48;
  #pragma unroll
  for (int j8 = 0; j8 < 6; ++j8) {
    bf16x8 o8;
    #pragma unroll
    for (int q = 0; q < 8; ++q) o8[q] = t[(seg * 48 + j8 * 8 + q) * 66 + n];
    *(bf16x8*)(dstrow + j8 * 8) = o8;
  }
}

// ---------------------------------------------------------------------------
// f: out[b] = P_b (192x192 bf16) * Y_b via yT (k-contig B). No LDS, no
// barriers: A and B fragments straight from global (P L2-hot, yT streamed).
// ---------------------------------------------------------------------------
__global__ __launch_bounds__(256, 4) void f_kernel(const bf16* __restrict__ yt,
                                                   const bf16* __restrict__ pb,
                                                   float* __restrict__ out)
{
  const int nc = blockIdx.x, b = blockIdx.y;
  const int tid = threadIdx.x;
  const int lane = tid & 63, w = tid >> 6;
  const int lo = lane & 15, hi = lane >> 4;
  const int rowbase = w * 48;
  const bf16* ytb = yt + ((size_t)b * HWN + nc * 64) * CC;
  const bf16* pbb = pb + (size_t)b * CC * CC;

  f32x4 acc[3][4];
  #pragma unroll
  for (int m = 0; m < 3; ++m)
    #pragma unroll
    for (int n = 0; n < 4; ++n) acc[m][n] = (f32x4){0.f, 0.f, 0.f, 0.f};

  #pragma unroll
  for (int ks = 0; ks < 6; ++ks) {
    const int d0 = ks * 32 + hi * 8;
    bf16x8 pa[3], yb[4];
    #pragma unroll
    for (int mt = 0; mt < 3; ++mt)
      pa[mt] = *(const bf16x8*)(pbb + (size_t)(rowbase + mt * 16 + lo) * CC + d0);
    #pragma unroll
    for (int nt = 0; nt < 4; ++nt)
      yb[nt] = *(const bf16x8*)(ytb + (size_t)(nt * 16 + lo) * CC + d0);
    #pragma unroll
    for (int mt = 0; mt < 3; ++mt)
      #pragma unroll
      for (int nt = 0; nt < 4; ++nt)
        acc[mt][nt] = __builtin_amdgcn_mfma_f32_16x16x32_bf16(pa[mt], yb[nt], acc[mt][nt], 0, 0, 0);
  }

  #pragma unroll
  for (int mt = 0; mt < 3; ++mt)
    #pragma unroll
    for (int nt = 0; nt < 4; ++nt)
      #pragma unroll
      for (int r = 0; r < 4; ++r) {
        int o = rowbase + mt * 16 + hi * 4 + r;
        out[((size_t)(b * CC + o)) * HWN + nc * 64 + nt * 16 + lo] = acc[mt][nt][r];
      }
}

// Fallback f (round-3 version): global fp32 Y + LDS gather.
__global__ __launch_bounds__(256) void f_fb_kernel(const float* __restrict__ y,
                                                   const bf16* __restrict__ pb,
                                                   float* __restrict__ out)
{
  const int nc = blockIdx.x, b = blockIdx.y;
  const int tid = threadIdx.x;
  const int lane = tid & 63, w = tid >> 6;
  const int lo = lane & 15, hi = lane >> 4;
  const int rowbase = w * 48;
  __shared__ bf16 ytl[32][68];

  f32x4 acc[3][4];
  #pragma unroll
  for (int m = 0; m < 3; ++m)
    #pragma unroll
    for (int n = 0; n < 4; ++n) acc[m][n] = (f32x4){0.f, 0.f, 0.f, 0.f};

  const int sd = tid >> 4;
  const int sn = (tid & 15) * 4;

  for (int ks = 0; ks < 6; ++ks) {
    const int d0 = ks * 32;
    __syncthreads();
    #pragma unroll
    for (int p = 0; p < 2; ++p) {
      int d = sd + p * 16;
      const float4 v = *(const float4*)(y + ((size_t)(b * CC + d0 + d)) * HWN + nc * 64 + sn);
      *(bf16x4v*)(&ytl[d][sn]) = (bf16x4v){(bf16)v.x, (bf16)v.y, (bf16)v.z, (bf16)v.w};
    }
    __syncthreads();

    bf16x8 pa[3];
    #pragma unroll
    for (int mt = 0; mt < 3; ++mt)
      pa[mt] = *(const bf16x8*)(pb + ((size_t)(b * CC + rowbase + mt * 16 + lo)) * CC + d0 + hi * 8);

    #pragma unroll
    for (int nt = 0; nt < 4; ++nt) {
      bf16x8 bq;
      #pragma unroll
      for (int j = 0; j < 8; ++j) bq[j] = ytl[hi * 8 + j][nt * 16 + lo];
      #pragma unroll
      for (int mt = 0; mt < 3; ++mt)
        acc[mt][nt] = __builtin_amdgcn_mfma_f32_16x16x32_bf16(pa[mt], bq, acc[mt][nt], 0, 0, 0);
    }
  }

  #pragma unroll
  for (int mt = 0; mt < 3; ++mt)
    #pragma unroll
    for (int nt = 0; nt < 4; ++nt)
      #pragma unroll
      for (int r = 0; r < 4; ++r) {
        int o = rowbase + mt * 16 + hi * 4 + r;
        out[((size_t)(b * CC + o)) * HWN + nc * 64 + nt * 16 + lo] = acc[mt][nt][r];
      }
}

extern "C" void kernel_launch(void* const* d_in, const int* in_sizes, int n_in,
                              void* d_out, int out_size, void* d_ws, size_t ws_size,
                              hipStream_t stream)
{
  (void)in_sizes; (void)n_in; (void)out_size;
  const float* x  = (const float*)d_in[0];
  const float* y  = (const float*)d_in[1];
  const float* Wq = (const float*)d_in[2];
  const float* Wk = (const float*)d_in[3];
  const float* Wv = (const float*)d_in[4];
  const float* Wo = (const float*)d_in[5];
  const float* temperature = (const float*)d_in[6];
  float* out = (float*)d_out;

  float* ws = (float*)d_ws;
  const size_t core_f = (size_t)KSPLIT * GN + GN + GN + ZN;   // gpart+gram+tuv+z
  const size_t need1 = core_f * 4 + (size_t)ZN * 2;           // + pb
  const size_t need2 = need1 + YTN * 2;                       // + yT

  if (ws_size >= need2) {
    float* gpart = ws;
    float* gram  = gpart + (size_t)KSPLIT * GN;
    float* tuv   = gram + GN;
    float* zbuf  = tuv + GN;
    bf16*  pbuf  = (bf16*)(zbuf + ZN);
    bf16*  ytb   = (bf16*)((char*)pbuf + (size_t)ZN * 2);

    tr_kernel<<<dim3(HWN / 64, BB), 256, 0, stream>>>(y, ytb);
    gram_kernel<<<dim3(KSPLIT, BB, 2), 512, 0, stream>>>(x, y, gpart, 0);
    reduce_kernel<<<GN / 256, 256, 0, stream>>>(gpart, gram);
    s1_kernel<<<dim3(8, BB, 3), 192, 0, stream>>>(gram, Wq, Wk, tuv);
    s2_kernel<<<dim3(NH, BB), 256, 0, stream>>>(tuv, Wq, Wk, Wv, temperature, zbuf);
    s3_kernel<<<dim3(8, BB), 192, 0, stream>>>(zbuf, Wo, pbuf);
    f_kernel<<<dim3(HWN / 64, BB), 256, 0, stream>>>(ytb, pbuf, out);
  } else if (ws_size >= need1) {
    float* gpart = ws;
    float* gram  = gpart + (size_t)KSPLIT * GN;
    float* tuv   = gram + GN;
    float* zbuf  = tuv + GN;
    bf16*  pbuf  = (bf16*)(zbuf + ZN);

    gram_kernel<<<dim3(KSPLIT, BB, 2), 512, 0, stream>>>(x, y, gpart, 0);
    reduce_kernel<<<GN / 256, 256, 0, stream>>>(gpart, gram);
    s1_kernel<<<dim3(8, BB, 3), 192, 0, stream>>>(gram, Wq, Wk, tuv);
    s2_kernel<<<dim3(NH, BB), 256, 0, stream>>>(tuv, Wq, Wk, Wv, temperature, zbuf);
    s3_kernel<<<dim3(8, BB), 192, 0, stream>>>(zbuf, Wo, pbuf);
    f_fb_kernel<<<dim3(HWN / 64, BB), 256, 0, stream>>>(y, pbuf, out);
  } else {
    float* gram = ws;
    float* tuv  = gram + GN;
    float* zbuf = tuv + GN;
    bf16*  pbuf = (bf16*)(zbuf + ZN);

    hipMemsetAsync(gram, 0, (size_t)GN * sizeof(float), stream);
    gram_kernel<<<dim3(KSPLIT, BB, 2), 512, 0, stream>>>(x, y, gram, 1);
    s1_kernel<<<dim3(8, BB, 3), 192, 0, stream>>>(gram, Wq, Wk, tuv);
    s2_kernel<<<dim3(NH, BB), 256, 0, stream>>>(tuv, Wq, Wk, Wv, temperature, zbuf);
    s3_kernel<<<dim3(8, BB), 192, 0, stream>>>(zbuf, Wo, pbuf);
    f_fb_kernel<<<dim3(HWN / 64, BB), 256, 0, stream>>>(y, pbuf, out);
  }
}